// Round 6
// baseline (451.409 us; speedup 1.0000x reference)
//
#include <hip/hip_runtime.h>
#include <hip/hip_bf16.h>
#include <math.h>

#define S_TOTAL 7681

typedef __attribute__((ext_vector_type(8))) short bf16x8;
typedef __attribute__((ext_vector_type(4))) float f32x4;

// fp32 -> bf16 round-to-nearest-even
__device__ __forceinline__ short f2b(float x) {
    union { float f; unsigned u; } v; v.f = x;
    unsigned r = v.u + 0x7FFFu + ((v.u >> 16) & 1u);
    return (short)(r >> 16);
}
__device__ __forceinline__ float b2f(unsigned short u) {
    union { unsigned u; float f; } t; t.u = ((unsigned)u) << 16; return t.f;
}

#define BM 128
#define BN 64
#define BK 32
#define KP 40

// ---------------------------------------------------------------------------
// Prologue (one dispatch): blocks [0,2208) transpose+convert all weights,
// blocks [2208,4129): out=src, xb=bf16(src), qb=bf16(src+pos).
// ---------------------------------------------------------------------------
#define N4_TOT 491584  // S*256/4
__global__ __launch_bounds__(256) void prologue_kernel(
    const float* __restrict__ s0, const float* __restrict__ s1,
    const float* __restrict__ s2, const float* __restrict__ s3,
    const float* __restrict__ s4, const float* __restrict__ s5,
    short* __restrict__ d0, short* __restrict__ d1, short* __restrict__ d2,
    short* __restrict__ d3, short* __restrict__ d4, short* __restrict__ d5,
    const float4* __restrict__ src, const float4* __restrict__ pos,
    float4* __restrict__ o, ushort4* __restrict__ xb, ushort4* __restrict__ qb)
{
    int b = blockIdx.x;
    if (b >= 2208) {
        int i = (b - 2208) * 256 + threadIdx.x;
        if (i < N4_TOT) {
            float4 v = src[i], p = pos[i];
            o[i] = v;
            ushort4 h, hq;
            h.x = (unsigned short)f2b(v.x); h.y = (unsigned short)f2b(v.y);
            h.z = (unsigned short)f2b(v.z); h.w = (unsigned short)f2b(v.w);
            hq.x = (unsigned short)f2b(v.x + p.x); hq.y = (unsigned short)f2b(v.y + p.y);
            hq.z = (unsigned short)f2b(v.z + p.z); hq.w = (unsigned short)f2b(v.w + p.w);
            xb[i] = h;
            qb[i] = hq;
        }
        return;
    }
    const int z = b / 736;
    int t = b - z * 736;
    const float* src_w; short* dst; int K, N, lt;
    if (t < 64)       { src_w = s0 + (size_t)z * 65536;  dst = d0 + (size_t)z * 65536;  K = 256;  N = 256;  lt = t; }
    else if (t < 128) { src_w = s1 + (size_t)z * 65536;  dst = d1 + (size_t)z * 98304;  K = 256;  N = 256;  lt = t - 64; }
    else if (t < 160) { src_w = s2 + (size_t)z * 32768;  dst = d2 + (size_t)z * 98304;  K = 256;  N = 128;  lt = t - 128; }
    else if (t < 224) { src_w = s3 + (size_t)z * 65536;  dst = d3 + (size_t)z * 65536;  K = 256;  N = 256;  lt = t - 160; }
    else if (t < 480) { src_w = s4 + (size_t)z * 262144; dst = d4 + (size_t)z * 262144; K = 256;  N = 1024; lt = t - 224; }
    else              { src_w = s5 + (size_t)z * 262144; dst = d5 + (size_t)z * 262144; K = 1024; N = 256;  lt = t - 480; }
    const int ntx = N >> 5;
    const int tk = (lt / ntx) << 5, tn = (lt % ntx) << 5;
    __shared__ float tile[32][33];
    const int cx = threadIdx.x & 31, cy = threadIdx.x >> 5;
    #pragma unroll
    for (int i = 0; i < 32; i += 8)
        tile[cy + i][cx] = src_w[(size_t)(tk + cy + i) * N + tn + cx];
    __syncthreads();
    #pragma unroll
    for (int i = 0; i < 32; i += 8)
        dst[(size_t)(tn + cy + i) * K + tk + cx] = f2b(tile[cx][cy + i]);
}

// ---------------------------------------------------------------------------
// Merged value + off/attn GEMM (K=256). grid (61, 10):
//  y in [0,4): value_bf[S][256] (bf16) = xb @ Wt_val^T + b_val
//  y in [4,10): offb[S][384] (fp32) = qb @ Wt_oa^T + {b_off|b_attn}
// ---------------------------------------------------------------------------
__global__ __launch_bounds__(256) void gemm_va_kernel(
    const short* __restrict__ xb, const short* __restrict__ qb,
    const short* __restrict__ Wt_val, const short* __restrict__ Wt_oa,
    const float* __restrict__ b_val, const float* __restrict__ b_off,
    const float* __restrict__ b_attn,
    short* __restrict__ value_bf, float* __restrict__ offbuf, int M)
{
    const int grp = (blockIdx.y >= 4);
    const short* A  = grp ? qb : xb;
    const short* Wt = grp ? Wt_oa : Wt_val;
    const int colBase = (grp ? (blockIdx.y - 4) : blockIdx.y) * BN;
    const int K = 256;

    __shared__ __align__(16) short As[BM * KP];
    __shared__ __align__(16) short Bs[BN * KP];
    const int tid = threadIdx.x;
    const int lane = tid & 63;
    const int wave = tid >> 6;
    const int rowBase = blockIdx.x * BM;

    const int ar = tid >> 1;
    const int ak = (tid & 1) * 16;
    const int br = tid >> 2;
    const int bk = (tid & 3) * 8;

    const int frow = lane & 15;
    const int fko  = (lane >> 4) * 8;
    const int wm = wave * 32;

    f32x4 acc[2][4] = {};

    const int aRow = rowBase + ar;
    const bool aOk = aRow < M;
    const short* Ap = A + (size_t)aRow * K + ak;
    const short* Bp = Wt + (size_t)(colBase + br) * K + bk;

    bf16x8 a0 = {}, a1 = {}, b0 = {};
    if (aOk) { a0 = *(const bf16x8*)Ap; a1 = *(const bf16x8*)(Ap + 8); }
    b0 = *(const bf16x8*)Bp;

    for (int k0 = 0; k0 < K; k0 += BK) {
        *(bf16x8*)&As[ar * KP + ak]     = a0;
        *(bf16x8*)&As[ar * KP + ak + 8] = a1;
        *(bf16x8*)&Bs[br * KP + bk]     = b0;
        __syncthreads();

        const int kn = k0 + BK;
        if (kn < K) {
            if (aOk) { a0 = *(const bf16x8*)(Ap + kn); a1 = *(const bf16x8*)(Ap + kn + 8); }
            b0 = *(const bf16x8*)(Bp + kn);
        }

        bf16x8 af0 = *(const bf16x8*)&As[(wm + frow) * KP + fko];
        bf16x8 af1 = *(const bf16x8*)&As[(wm + 16 + frow) * KP + fko];
        #pragma unroll
        for (int j = 0; j < 4; ++j) {
            bf16x8 bfj = *(const bf16x8*)&Bs[(j * 16 + frow) * KP + fko];
            acc[0][j] = __builtin_amdgcn_mfma_f32_16x16x32_bf16(af0, bfj, acc[0][j], 0, 0, 0);
            acc[1][j] = __builtin_amdgcn_mfma_f32_16x16x32_bf16(af1, bfj, acc[1][j], 0, 0, 0);
        }
        __syncthreads();
    }

    const int erow = (lane >> 4) * 4;
    const int ecol = lane & 15;
    #pragma unroll
    for (int mi = 0; mi < 2; ++mi) {
        #pragma unroll
        for (int j = 0; j < 4; ++j) {
            int col = colBase + j * 16 + ecol;
            float bias = grp ? (col < 256 ? b_off[col] : b_attn[col - 256]) : b_val[col];
            #pragma unroll
            for (int r = 0; r < 4; ++r) {
                int row = rowBase + wm + mi * 16 + erow + r;
                if (row < M) {
                    float v = acc[mi][j][r] + bias;
                    if (grp) offbuf[(size_t)row * 384 + col] = v;
                    else     value_bf[(size_t)row * 256 + col] = f2b(v);
                }
            }
        }
    }
}

// ---------------------------------------------------------------------------
// Plain bf16 MFMA GEMM + bias + relu -> bf16 (ff1).
// ---------------------------------------------------------------------------
__global__ __launch_bounds__(256) void gemm_ff1_kernel(
    const short* __restrict__ A, const short* __restrict__ Wt,
    const float* __restrict__ bias, short* __restrict__ Cv,
    int M, int N, int K)
{
    __shared__ __align__(16) short As[BM * KP];
    __shared__ __align__(16) short Bs[BN * KP];
    const int tid = threadIdx.x;
    const int lane = tid & 63;
    const int wave = tid >> 6;
    const int rowBase = blockIdx.x * BM;
    const int colBase = blockIdx.y * BN;

    const int ar = tid >> 1;
    const int ak = (tid & 1) * 16;
    const int br = tid >> 2;
    const int bk = (tid & 3) * 8;

    const int frow = lane & 15;
    const int fko  = (lane >> 4) * 8;
    const int wm = wave * 32;

    f32x4 acc[2][4] = {};

    const int aRow = rowBase + ar;
    const bool aOk = aRow < M;
    const short* Ap = A + (size_t)aRow * K + ak;
    const short* Bp = Wt + (size_t)(colBase + br) * K + bk;

    bf16x8 a0 = {}, a1 = {}, b0 = {};
    if (aOk) { a0 = *(const bf16x8*)Ap; a1 = *(const bf16x8*)(Ap + 8); }
    b0 = *(const bf16x8*)Bp;

    for (int k0 = 0; k0 < K; k0 += BK) {
        *(bf16x8*)&As[ar * KP + ak]     = a0;
        *(bf16x8*)&As[ar * KP + ak + 8] = a1;
        *(bf16x8*)&Bs[br * KP + bk]     = b0;
        __syncthreads();

        const int kn = k0 + BK;
        if (kn < K) {
            if (aOk) { a0 = *(const bf16x8*)(Ap + kn); a1 = *(const bf16x8*)(Ap + kn + 8); }
            b0 = *(const bf16x8*)(Bp + kn);
        }

        bf16x8 af0 = *(const bf16x8*)&As[(wm + frow) * KP + fko];
        bf16x8 af1 = *(const bf16x8*)&As[(wm + 16 + frow) * KP + fko];
        #pragma unroll
        for (int j = 0; j < 4; ++j) {
            bf16x8 bfj = *(const bf16x8*)&Bs[(j * 16 + frow) * KP + fko];
            acc[0][j] = __builtin_amdgcn_mfma_f32_16x16x32_bf16(af0, bfj, acc[0][j], 0, 0, 0);
            acc[1][j] = __builtin_amdgcn_mfma_f32_16x16x32_bf16(af1, bfj, acc[1][j], 0, 0, 0);
        }
        __syncthreads();
    }

    const int erow = (lane >> 4) * 4;
    const int ecol = lane & 15;
    #pragma unroll
    for (int mi = 0; mi < 2; ++mi) {
        #pragma unroll
        for (int j = 0; j < 4; ++j) {
            #pragma unroll
            for (int r = 0; r < 4; ++r) {
                int row = rowBase + wm + mi * 16 + erow + r;
                if (row < M) {
                    int col = colBase + j * 16 + ecol;
                    float v = fmaxf(acc[mi][j][r] + bias[col], 0.f);
                    Cv[(size_t)row * N + col] = f2b(v);
                }
            }
        }
    }
}

// ---------------------------------------------------------------------------
// MSDA sampling v5: 8 queries/block, 2 queries/wave (32 lanes each:
// 8 heads x 4 dim-groups of 8), ushort8 (16B) gathers from bf16 value.
// LDS cut to 24.6 KB by phase-aliasing sIdx/sWgt onto the soff staging
// region (point records computed into registers, barrier, then overwrite).
// grid = 968 = 8*121, XCD-contiguous swizzle.
// ---------------------------------------------------------------------------
__global__ __launch_bounds__(256) void msda_kernel(
    const short* __restrict__ value, const float* __restrict__ offb,
    short* __restrict__ msdab)
{
    __shared__ __align__(16) char scratch[24576];
    float*   soff = (float*)scratch;               // phase 1: 12288 B
    ushort4* sIdx = (ushort4*)scratch;             // phase 2:  8192 B
    float4*  sWgt = (float4*)(scratch + 8192);     // phase 2: 16384 B

    const int bid = blockIdx.x;
    const int sb = (bid & 7) * 121 + (bid >> 3);
    const int q0 = sb * 8;
    if (q0 >= S_TOTAL) return;
    const int tid = threadIdx.x;

    // stage 8 rows of offb as float4 (96 float4/row)
    {
        const float4* src4 = (const float4*)offb;
        float4* soff4 = (float4*)soff;
        #pragma unroll
        for (int i = tid; i < 768; i += 256) {
            int qi = i / 96, j = i - qi * 96;
            int q = min(q0 + qi, S_TOTAL - 1);
            soff4[qi * 96 + j] = src4[(size_t)q * 96 + j];
        }
    }
    __syncthreads();

    // softmax per (query, head): 64 pairs, in place
    if (tid < 64) {
        const int qi = tid >> 3, m = tid & 7;
        float* lg = &soff[qi * 384 + 256 + m * 16];
        float mx = -1e30f;
        #pragma unroll
        for (int k = 0; k < 16; ++k) mx = fmaxf(mx, lg[k]);
        float e[16], sum = 0.f;
        #pragma unroll
        for (int k = 0; k < 16; ++k) { e[k] = expf(lg[k] - mx); sum += e[k]; }
        float inv = 1.f / sum;
        #pragma unroll
        for (int k = 0; k < 16; ++k) lg[k] = e[k] * inv;
    }
    __syncthreads();

    // per-(q, m, lvl, p) records into REGISTERS (4 per thread), then alias
    ushort4 rid[4];
    float4  rw[4];
    #pragma unroll
    for (int k = 0; k < 4; ++k) {
        const int it = tid + k * 256;
        const int qi = it >> 7, i = it & 127;
        const int lvl = (i >> 2) & 3;
        const int q = min(q0 + qi, S_TOTAL - 1);

        float refx, refy;
        if (q < 5776)      { int u = q;        int r = u / 76, c = u % 76; refx = (c + 0.5f) / 76.f; refy = (r + 0.5f) / 76.f; }
        else if (q < 7220) { int u = q - 5776; int r = u / 38, c = u % 38; refx = (c + 0.5f) / 38.f; refy = (r + 0.5f) / 38.f; }
        else if (q < 7581) { int u = q - 7220; int r = u / 19, c = u % 19; refx = (c + 0.5f) / 19.f; refy = (r + 0.5f) / 19.f; }
        else               { int u = q - 7581; int r = u / 10, c = u % 10; refx = (c + 0.5f) / 10.f; refy = (r + 0.5f) / 10.f; }

        const int LVL_HW[4] = {76, 38, 19, 10};
        const int LVL_ST[4] = {0, 5776, 7220, 7581};
        const int W = LVL_HW[lvl];
        const float fW = (float)W;

        float ox = soff[qi * 384 + i * 2];
        float oy = soff[qi * 384 + i * 2 + 1];
        float aw = soff[qi * 384 + 256 + i];

        float x = refx * fW + ox - 0.5f;
        float y = refy * fW + oy - 0.5f;
        float x0f = floorf(x), y0f = floorf(y);
        int x0 = (int)x0f, y0 = (int)y0f;
        float dx = x - x0f, dy = y - y0f;

        bool vx0 = (x0 >= 0) & (x0 < W);
        bool vx1 = (x0 >= -1) & (x0 < W - 1);
        bool vy0 = (y0 >= 0) & (y0 < W);
        bool vy1 = (y0 >= -1) & (y0 < W - 1);
        int xc0 = min(max(x0, 0), W - 1), xc1 = min(max(x0 + 1, 0), W - 1);
        int yc0 = min(max(y0, 0), W - 1), yc1 = min(max(y0 + 1, 0), W - 1);
        int base = LVL_ST[lvl];
        rid[k].x = (unsigned short)(base + yc0 * W + xc0);
        rid[k].y = (unsigned short)(base + yc0 * W + xc1);
        rid[k].z = (unsigned short)(base + yc1 * W + xc0);
        rid[k].w = (unsigned short)(base + yc1 * W + xc1);
        rw[k].x = (vy0 && vx0) ? (1.f - dy) * (1.f - dx) * aw : 0.f;
        rw[k].y = (vy0 && vx1) ? (1.f - dy) * dx * aw : 0.f;
        rw[k].z = (vy1 && vx0) ? dy * (1.f - dx) * aw : 0.f;
        rw[k].w = (vy1 && vx1) ? dy * dx * aw : 0.f;
    }
    __syncthreads();   // all soff reads done; safe to overwrite
    #pragma unroll
    for (int k = 0; k < 4; ++k) {
        sIdx[tid + k * 256] = rid[k];
        sWgt[tid + k * 256] = rw[k];
    }
    __syncthreads();

    const int lane = tid & 63;
    const int qi = (tid >> 6) * 2 + (lane >> 5);
    const int q = q0 + qi;
    if (q >= S_TOTAL) return;
    const int l32 = lane & 31;
    const int h = l32 >> 2, dg = l32 & 3;
    const short* vcol = value + h * 32 + dg * 8;
    const int itb = qi * 128 + (h << 4);

    float a[8] = {};
    #pragma unroll
    for (int pt = 0; pt < 16; ++pt) {
        const ushort4 id = sIdx[itb + pt];
        const float4 w = sWgt[itb + pt];
        bf16x8 v0 = *(const bf16x8*)(vcol + ((size_t)id.x << 8));
        bf16x8 v1 = *(const bf16x8*)(vcol + ((size_t)id.y << 8));
        bf16x8 v2 = *(const bf16x8*)(vcol + ((size_t)id.z << 8));
        bf16x8 v3 = *(const bf16x8*)(vcol + ((size_t)id.w << 8));
        #pragma unroll
        for (int e = 0; e < 8; ++e)
            a[e] += w.x * b2f((unsigned short)v0[e]) + w.y * b2f((unsigned short)v1[e])
                  + w.z * b2f((unsigned short)v2[e]) + w.w * b2f((unsigned short)v3[e]);
    }
    bf16x8 o;
    #pragma unroll
    for (int e = 0; e < 8; ++e) o[e] = f2b(a[e]);
    *(bf16x8*)(msdab + (size_t)q * 256 + h * 32 + dg * 8) = o;
}

// ---------------------------------------------------------------------------
// GEMM (N=256) + residual + LN, BM=16 rows/block (481 blocks). A from global.
// Writes out fp32, xb bf16, (WRITEQ) qb = bf16(out + pos).
// ---------------------------------------------------------------------------
template<int WRITEQ>
__global__ __launch_bounds__(256) void gemm_ln16_kernel(
    const short* __restrict__ A, const short* __restrict__ Wt,
    const float* __restrict__ bias, const float* __restrict__ g,
    const float* __restrict__ bln, const float* __restrict__ pos,
    float* __restrict__ out, short* __restrict__ xb, short* __restrict__ qb,
    int M, int K)
{
    __shared__ __align__(16) short As[16 * KP];
    __shared__ __align__(16) short Bs[256 * KP];
    __shared__ float rsum[16][4], rsq[16][4], smu[16], srs[16];

    const int tid = threadIdx.x;
    const int lane = tid & 63;
    const int wave = tid >> 6;
    const int rowBase = blockIdx.x * 16;

    const int frow = lane & 15;
    const int fko  = (lane >> 4) * 8;

    f32x4 acc[4] = {};

    const int ar = tid >> 1;             // valid for tid<32
    const int ak = (tid & 1) * 16;
    const int aRow = rowBase + ar;
    const bool aOk = (tid < 32) && (aRow < M);
    const short* Ap = A + (size_t)aRow * K + ak;
    const short* Bp = Wt + (size_t)tid * K;

    bf16x8 a0 = {}, a1 = {};
    if (aOk) { a0 = *(const bf16x8*)Ap; a1 = *(const bf16x8*)(Ap + 8); }
    bf16x8 w0 = *(const bf16x8*)(Bp);      bf16x8 w1 = *(const bf16x8*)(Bp + 8);
    bf16x8 w2 = *(const bf16x8*)(Bp + 16); bf16x8 w3 = *(const bf16x8*)(Bp + 24);

    for (int k0 = 0; k0 < K; k0 += BK) {
        if (tid < 32) {
            *(bf16x8*)&As[ar * KP + ak]     = a0;
            *(bf16x8*)&As[ar * KP + ak + 8] = a1;
        }
        *(bf16x8*)&Bs[tid * KP + 0]  = w0;
        *(bf16x8*)&Bs[tid * KP + 8]  = w1;
        *(bf16x8*)&Bs[tid * KP + 16] = w2;
        *(bf16x8*)&Bs[tid * KP + 24] = w3;
        __syncthreads();

        const int kn = k0 + BK;
        if (kn < K) {
            if (aOk) { a0 = *(const bf16x8*)(Ap + kn); a1 = *(const bf16x8*)(Ap + kn + 8); }
            w0 = *(const bf16x8*)(Bp + kn);      w1 = *(const bf16x8*)(Bp + kn + 8);
            w2 = *(const bf16x8*)(Bp + kn + 16); w3 = *(const bf16x8*)(Bp + kn + 24);
        }

        bf16x8 af = *(const bf16x8*)&As[frow * KP + fko];
        #pragma unroll
        for (int j = 0; j < 4; ++j) {
            bf16x8 bfj = *(const bf16x8*)&Bs[(wave * 64 + j * 16 + frow) * KP + fko];
            acc[j] = __builtin_amdgcn_mfma_f32_16x16x32_bf16(af, bfj, acc[j], 0, 0, 0);
        }
        __syncthreads();
    }

    const int erow = (lane >> 4) * 4;
    const int ecol = lane & 15;
    float x[4][4];
    #pragma unroll
    for (int j = 0; j < 4; ++j)
        #pragma unroll
        for (int r = 0; r < 4; ++r) {
            int row = rowBase + erow + r;
            int col = wave * 64 + j * 16 + ecol;
            float res = (row < M) ? out[(size_t)row * 256 + col] : 0.f;
            x[j][r] = acc[j][r] + bias[col] + res;
        }

    #pragma unroll
    for (int r = 0; r < 4; ++r) {
        float s1 = x[0][r] + x[1][r] + x[2][r] + x[3][r];
        float s2 = x[0][r]*x[0][r] + x[1][r]*x[1][r] + x[2][r]*x[2][r] + x[3][r]*x[3][r];
        #pragma unroll
        for (int o = 1; o < 16; o <<= 1) {
            s1 += __shfl_xor(s1, o);
            s2 += __shfl_xor(s2, o);
        }
        if ((lane & 15) == 0) {
            rsum[erow + r][wave] = s1;
            rsq [erow + r][wave] = s2;
        }
    }
    __syncthreads();
    if (tid < 16) {
        float S1 = rsum[tid][0] + rsum[tid][1] + rsum[tid][2] + rsum[tid][3];
        float S2 = rsq[tid][0] + rsq[tid][1] + rsq[tid][2] + rsq[tid][3];
        float mu = S1 * (1.f / 256.f);
        smu[tid] = mu;
        srs[tid] = rsqrtf(S2 * (1.f / 256.f) - mu * mu + 1e-5f);
    }
    __syncthreads();

    #pragma unroll
    for (int r = 0; r < 4; ++r) {
        int lrow = erow + r;
        int row = rowBase + lrow;
        if (row >= M) continue;
        float mu = smu[lrow], rs = srs[lrow];
        #pragma unroll
        for (int j = 0; j < 4; ++j) {
            int col = wave * 64 + j * 16 + ecol;
            float y = (x[j][r] - mu) * rs * g[col] + bln[col];
            out[(size_t)row * 256 + col] = y;
            xb[(size_t)row * 256 + col] = f2b(y);
            if (WRITEQ)
                qb[(size_t)row * 256 + col] = f2b(y + pos[(size_t)row * 256 + col]);
        }
    }
}

// ---------------------------------------------------------------------------
extern "C" void kernel_launch(void* const* d_in, const int* in_sizes, int n_in,
                              void* d_out, int out_size, void* d_ws, size_t ws_size,
                              hipStream_t stream) {
    const float* src    = (const float*)d_in[0];
    const float* pos    = (const float*)d_in[1];
    const float* W_off  = (const float*)d_in[6];
    const float* b_off  = (const float*)d_in[7];
    const float* W_attn = (const float*)d_in[8];
    const float* b_attn = (const float*)d_in[9];
    const float* W_val  = (const float*)d_in[10];
    const float* b_val  = (const float*)d_in[11];
    const float* W_out  = (const float*)d_in[12];
    const float* b_out  = (const float*)d_in[13];
    const float* ln1_g  = (const float*)d_in[14];
    const float* ln1_b  = (const float*)d_in[15];
    const float* W_ff1  = (const float*)d_in[16];
    const float* b_ff1  = (const float*)d_in[17];
    const float* W_ff2  = (const float*)d_in[18];
    const float* b_ff2  = (const float*)d_in[19];
    const float* ln2_g  = (const float*)d_in[20];
    const float* ln2_b  = (const float*)d_in[21];

    const size_t S = S_TOTAL;
    float* out = (float*)d_out;

    // --- workspace layout ---
    short* wt = (short*)d_ws;
    short* Wt_val = wt;             // 3 x [256][256]
    short* Wt_oa  = wt + 196608;    // 3 x [384][256] (off rows 0-255, attn 256-383)
    short* Wt_out = wt + 491520;    // 3 x [256][256]
    short* Wt_ff1 = wt + 688128;    // 3 x [1024][256]
    short* Wt_ff2 = wt + 1474560;   // 3 x [256][1024]
    float* fbase  = (float*)d_ws + 1131648;
    short* xb       = (short*)fbase;               // [S][256] bf16
    short* qb       = (short*)(fbase + 128 * S);   // [S][256] bf16
    short* value_bf = (short*)(fbase + 256 * S);   // [S][256] bf16
    float* offb     = fbase + 384 * S;             // [S][384] fp32
    short* msdab    = (short*)(fbase + 768 * S);   // [S][256] bf16
    short* hid      = (short*)(fbase + 256 * S);   // [S][1024] bf16 (FFN; overlaps value+offb)

    prologue_kernel<<<4129, 256, 0, stream>>>(
        W_val, W_off, W_attn, W_out, W_ff1, W_ff2,
        Wt_val, Wt_oa, Wt_oa + 65536, Wt_out, Wt_ff1, Wt_ff2,
        (const float4*)src, (const float4*)pos,
        (float4*)out, (ushort4*)xb, (ushort4*)qb);

    const int MB = (S_TOTAL + BM - 1) / BM;   // 61
    const int LB = (S_TOTAL + 15) / 16;       // 481

    for (int l = 0; l < 3; ++l) {
        // value (bf16) + off/attn (fp32) in one dispatch
        gemm_va_kernel<<<dim3(MB, 10), 256, 0, stream>>>(
            xb, qb, Wt_val + (size_t)l * 65536, Wt_oa + (size_t)l * 98304,
            b_val + (size_t)l * 256, b_off + (size_t)l * 256, b_attn + (size_t)l * 128,
            value_bf, offb, S_TOTAL);
        // sampling -> bf16 msdab
        msda_kernel<<<968, 256, 0, stream>>>(value_bf, offb, msdab);
        // out = LN1(out + msdab @ Wout + bout); xb = bf16(out)
        gemm_ln16_kernel<0><<<LB, 256, 0, stream>>>(
            msdab, Wt_out + (size_t)l * 65536, b_out + (size_t)l * 256,
            ln1_g + (size_t)l * 256, ln1_b + (size_t)l * 256, pos,
            out, xb, qb, S_TOTAL, 256);
        // hid = bf16(relu(xb @ Wff1 + b))
        gemm_ff1_kernel<<<dim3(MB, 16), 256, 0, stream>>>(
            xb, Wt_ff1 + (size_t)l * 262144, b_ff1 + (size_t)l * 1024, hid,
            S_TOTAL, 1024, 256);
        // out = LN2(out + hid @ Wff2 + b); xb, qb for next layer
        gemm_ln16_kernel<1><<<LB, 256, 0, stream>>>(
            hid, Wt_ff2 + (size_t)l * 262144, b_ff2 + (size_t)l * 256,
            ln2_g + (size_t)l * 256, ln2_b + (size_t)l * 256, pos,
            out, xb, qb, S_TOTAL, 1024);
    }
}

// Round 7
// 440.478 us; speedup vs baseline: 1.0248x; 1.0248x over previous
//
#include <hip/hip_runtime.h>
#include <hip/hip_bf16.h>
#include <math.h>

#define S_TOTAL 7681

typedef __attribute__((ext_vector_type(8))) short bf16x8;
typedef __attribute__((ext_vector_type(4))) float f32x4;

// fp32 -> bf16 round-to-nearest-even
__device__ __forceinline__ short f2b(float x) {
    union { float f; unsigned u; } v; v.f = x;
    unsigned r = v.u + 0x7FFFu + ((v.u >> 16) & 1u);
    return (short)(r >> 16);
}
__device__ __forceinline__ float b2f(unsigned short u) {
    union { unsigned u; float f; } t; t.u = ((unsigned)u) << 16; return t.f;
}

#define BM 128
#define BN 64
#define BK 32
#define KP 40

// ---------------------------------------------------------------------------
// Prologue (one dispatch): blocks [0,2208) transpose+convert all weights,
// blocks [2208,4129): out=src, xb=bf16(src), qb=bf16(src+pos).
// ---------------------------------------------------------------------------
#define N4_TOT 491584  // S*256/4
__global__ __launch_bounds__(256) void prologue_kernel(
    const float* __restrict__ s0, const float* __restrict__ s1,
    const float* __restrict__ s2, const float* __restrict__ s3,
    const float* __restrict__ s4, const float* __restrict__ s5,
    short* __restrict__ d0, short* __restrict__ d1, short* __restrict__ d2,
    short* __restrict__ d3, short* __restrict__ d4, short* __restrict__ d5,
    const float4* __restrict__ src, const float4* __restrict__ pos,
    float4* __restrict__ o, ushort4* __restrict__ xb, ushort4* __restrict__ qb)
{
    int b = blockIdx.x;
    if (b >= 2208) {
        int i = (b - 2208) * 256 + threadIdx.x;
        if (i < N4_TOT) {
            float4 v = src[i], p = pos[i];
            o[i] = v;
            ushort4 h, hq;
            h.x = (unsigned short)f2b(v.x); h.y = (unsigned short)f2b(v.y);
            h.z = (unsigned short)f2b(v.z); h.w = (unsigned short)f2b(v.w);
            hq.x = (unsigned short)f2b(v.x + p.x); hq.y = (unsigned short)f2b(v.y + p.y);
            hq.z = (unsigned short)f2b(v.z + p.z); hq.w = (unsigned short)f2b(v.w + p.w);
            xb[i] = h;
            qb[i] = hq;
        }
        return;
    }
    const int z = b / 736;
    int t = b - z * 736;
    const float* src_w; short* dst; int K, N, lt;
    if (t < 64)       { src_w = s0 + (size_t)z * 65536;  dst = d0 + (size_t)z * 65536;  K = 256;  N = 256;  lt = t; }
    else if (t < 128) { src_w = s1 + (size_t)z * 65536;  dst = d1 + (size_t)z * 98304;  K = 256;  N = 256;  lt = t - 64; }
    else if (t < 160) { src_w = s2 + (size_t)z * 32768;  dst = d2 + (size_t)z * 98304;  K = 256;  N = 128;  lt = t - 128; }
    else if (t < 224) { src_w = s3 + (size_t)z * 65536;  dst = d3 + (size_t)z * 65536;  K = 256;  N = 256;  lt = t - 160; }
    else if (t < 480) { src_w = s4 + (size_t)z * 262144; dst = d4 + (size_t)z * 262144; K = 256;  N = 1024; lt = t - 224; }
    else              { src_w = s5 + (size_t)z * 262144; dst = d5 + (size_t)z * 262144; K = 1024; N = 256;  lt = t - 480; }
    const int ntx = N >> 5;
    const int tk = (lt / ntx) << 5, tn = (lt % ntx) << 5;
    __shared__ float tile[32][33];
    const int cx = threadIdx.x & 31, cy = threadIdx.x >> 5;
    #pragma unroll
    for (int i = 0; i < 32; i += 8)
        tile[cy + i][cx] = src_w[(size_t)(tk + cy + i) * N + tn + cx];
    __syncthreads();
    #pragma unroll
    for (int i = 0; i < 32; i += 8)
        dst[(size_t)(tn + cy + i) * K + tk + cx] = f2b(tile[cx][cy + i]);
}

// ---------------------------------------------------------------------------
// Merged value + off/attn GEMM (K=256). grid (61, 10):
//  y in [0,4): value_bf[S][256] (bf16) = xb @ Wt_val^T + b_val
//  y in [4,10): offb[S][384] (fp32) = qb @ Wt_oa^T + {b_off|b_attn}
// ---------------------------------------------------------------------------
__global__ __launch_bounds__(256) void gemm_va_kernel(
    const short* __restrict__ xb, const short* __restrict__ qb,
    const short* __restrict__ Wt_val, const short* __restrict__ Wt_oa,
    const float* __restrict__ b_val, const float* __restrict__ b_off,
    const float* __restrict__ b_attn,
    short* __restrict__ value_bf, float* __restrict__ offbuf, int M)
{
    const int grp = (blockIdx.y >= 4);
    const short* A  = grp ? qb : xb;
    const short* Wt = grp ? Wt_oa : Wt_val;
    const int colBase = (grp ? (blockIdx.y - 4) : blockIdx.y) * BN;
    const int K = 256;

    __shared__ __align__(16) short As[BM * KP];
    __shared__ __align__(16) short Bs[BN * KP];
    const int tid = threadIdx.x;
    const int lane = tid & 63;
    const int wave = tid >> 6;
    const int rowBase = blockIdx.x * BM;

    const int ar = tid >> 1;
    const int ak = (tid & 1) * 16;
    const int br = tid >> 2;
    const int bk = (tid & 3) * 8;

    const int frow = lane & 15;
    const int fko  = (lane >> 4) * 8;
    const int wm = wave * 32;

    f32x4 acc[2][4] = {};

    const int aRow = rowBase + ar;
    const bool aOk = aRow < M;
    const short* Ap = A + (size_t)aRow * K + ak;
    const short* Bp = Wt + (size_t)(colBase + br) * K + bk;

    bf16x8 a0 = {}, a1 = {}, b0 = {};
    if (aOk) { a0 = *(const bf16x8*)Ap; a1 = *(const bf16x8*)(Ap + 8); }
    b0 = *(const bf16x8*)Bp;

    for (int k0 = 0; k0 < K; k0 += BK) {
        *(bf16x8*)&As[ar * KP + ak]     = a0;
        *(bf16x8*)&As[ar * KP + ak + 8] = a1;
        *(bf16x8*)&Bs[br * KP + bk]     = b0;
        __syncthreads();

        const int kn = k0 + BK;
        if (kn < K) {
            if (aOk) { a0 = *(const bf16x8*)(Ap + kn); a1 = *(const bf16x8*)(Ap + kn + 8); }
            b0 = *(const bf16x8*)(Bp + kn);
        }

        bf16x8 af0 = *(const bf16x8*)&As[(wm + frow) * KP + fko];
        bf16x8 af1 = *(const bf16x8*)&As[(wm + 16 + frow) * KP + fko];
        #pragma unroll
        for (int j = 0; j < 4; ++j) {
            bf16x8 bfj = *(const bf16x8*)&Bs[(j * 16 + frow) * KP + fko];
            acc[0][j] = __builtin_amdgcn_mfma_f32_16x16x32_bf16(af0, bfj, acc[0][j], 0, 0, 0);
            acc[1][j] = __builtin_amdgcn_mfma_f32_16x16x32_bf16(af1, bfj, acc[1][j], 0, 0, 0);
        }
        __syncthreads();
    }

    const int erow = (lane >> 4) * 4;
    const int ecol = lane & 15;
    #pragma unroll
    for (int mi = 0; mi < 2; ++mi) {
        #pragma unroll
        for (int j = 0; j < 4; ++j) {
            int col = colBase + j * 16 + ecol;
            float bias = grp ? (col < 256 ? b_off[col] : b_attn[col - 256]) : b_val[col];
            #pragma unroll
            for (int r = 0; r < 4; ++r) {
                int row = rowBase + wm + mi * 16 + erow + r;
                if (row < M) {
                    float v = acc[mi][j][r] + bias;
                    if (grp) offbuf[(size_t)row * 384 + col] = v;
                    else     value_bf[(size_t)row * 256 + col] = f2b(v);
                }
            }
        }
    }
}

// ---------------------------------------------------------------------------
// Plain bf16 MFMA GEMM + bias + relu -> bf16 (ff1).
// ---------------------------------------------------------------------------
__global__ __launch_bounds__(256) void gemm_ff1_kernel(
    const short* __restrict__ A, const short* __restrict__ Wt,
    const float* __restrict__ bias, short* __restrict__ Cv,
    int M, int N, int K)
{
    __shared__ __align__(16) short As[BM * KP];
    __shared__ __align__(16) short Bs[BN * KP];
    const int tid = threadIdx.x;
    const int lane = tid & 63;
    const int wave = tid >> 6;
    const int rowBase = blockIdx.x * BM;
    const int colBase = blockIdx.y * BN;

    const int ar = tid >> 1;
    const int ak = (tid & 1) * 16;
    const int br = tid >> 2;
    const int bk = (tid & 3) * 8;

    const int frow = lane & 15;
    const int fko  = (lane >> 4) * 8;
    const int wm = wave * 32;

    f32x4 acc[2][4] = {};

    const int aRow = rowBase + ar;
    const bool aOk = aRow < M;
    const short* Ap = A + (size_t)aRow * K + ak;
    const short* Bp = Wt + (size_t)(colBase + br) * K + bk;

    bf16x8 a0 = {}, a1 = {}, b0 = {};
    if (aOk) { a0 = *(const bf16x8*)Ap; a1 = *(const bf16x8*)(Ap + 8); }
    b0 = *(const bf16x8*)Bp;

    for (int k0 = 0; k0 < K; k0 += BK) {
        *(bf16x8*)&As[ar * KP + ak]     = a0;
        *(bf16x8*)&As[ar * KP + ak + 8] = a1;
        *(bf16x8*)&Bs[br * KP + bk]     = b0;
        __syncthreads();

        const int kn = k0 + BK;
        if (kn < K) {
            if (aOk) { a0 = *(const bf16x8*)(Ap + kn); a1 = *(const bf16x8*)(Ap + kn + 8); }
            b0 = *(const bf16x8*)(Bp + kn);
        }

        bf16x8 af0 = *(const bf16x8*)&As[(wm + frow) * KP + fko];
        bf16x8 af1 = *(const bf16x8*)&As[(wm + 16 + frow) * KP + fko];
        #pragma unroll
        for (int j = 0; j < 4; ++j) {
            bf16x8 bfj = *(const bf16x8*)&Bs[(j * 16 + frow) * KP + fko];
            acc[0][j] = __builtin_amdgcn_mfma_f32_16x16x32_bf16(af0, bfj, acc[0][j], 0, 0, 0);
            acc[1][j] = __builtin_amdgcn_mfma_f32_16x16x32_bf16(af1, bfj, acc[1][j], 0, 0, 0);
        }
        __syncthreads();
    }

    const int erow = (lane >> 4) * 4;
    const int ecol = lane & 15;
    #pragma unroll
    for (int mi = 0; mi < 2; ++mi) {
        #pragma unroll
        for (int j = 0; j < 4; ++j) {
            #pragma unroll
            for (int r = 0; r < 4; ++r) {
                int row = rowBase + wm + mi * 16 + erow + r;
                if (row < M) {
                    int col = colBase + j * 16 + ecol;
                    float v = fmaxf(acc[mi][j][r] + bias[col], 0.f);
                    Cv[(size_t)row * N + col] = f2b(v);
                }
            }
        }
    }
}

// ---------------------------------------------------------------------------
// MSDA sampling v5: 8 queries/block, 2 queries/wave (32 lanes each:
// 8 heads x 4 dim-groups of 8), ushort8 (16B) gathers from bf16 value.
// LDS 24.6 KB via phase-aliasing sIdx/sWgt onto the soff staging region.
// grid = 968 = 8*121, XCD-contiguous swizzle.
// ---------------------------------------------------------------------------
__global__ __launch_bounds__(256) void msda_kernel(
    const short* __restrict__ value, const float* __restrict__ offb,
    short* __restrict__ msdab)
{
    __shared__ __align__(16) char scratch[24576];
    float*   soff = (float*)scratch;               // phase 1: 12288 B
    ushort4* sIdx = (ushort4*)scratch;             // phase 2:  8192 B
    float4*  sWgt = (float4*)(scratch + 8192);     // phase 2: 16384 B

    const int bid = blockIdx.x;
    const int sb = (bid & 7) * 121 + (bid >> 3);
    const int q0 = sb * 8;
    if (q0 >= S_TOTAL) return;
    const int tid = threadIdx.x;

    // stage 8 rows of offb as float4 (96 float4/row)
    {
        const float4* src4 = (const float4*)offb;
        float4* soff4 = (float4*)soff;
        #pragma unroll
        for (int i = tid; i < 768; i += 256) {
            int qi = i / 96, j = i - qi * 96;
            int q = min(q0 + qi, S_TOTAL - 1);
            soff4[qi * 96 + j] = src4[(size_t)q * 96 + j];
        }
    }
    __syncthreads();

    // softmax per (query, head): 64 pairs, in place
    if (tid < 64) {
        const int qi = tid >> 3, m = tid & 7;
        float* lg = &soff[qi * 384 + 256 + m * 16];
        float mx = -1e30f;
        #pragma unroll
        for (int k = 0; k < 16; ++k) mx = fmaxf(mx, lg[k]);
        float e[16], sum = 0.f;
        #pragma unroll
        for (int k = 0; k < 16; ++k) { e[k] = expf(lg[k] - mx); sum += e[k]; }
        float inv = 1.f / sum;
        #pragma unroll
        for (int k = 0; k < 16; ++k) lg[k] = e[k] * inv;
    }
    __syncthreads();

    // per-(q, m, lvl, p) records into REGISTERS (4 per thread), then alias
    ushort4 rid[4];
    float4  rw[4];
    #pragma unroll
    for (int k = 0; k < 4; ++k) {
        const int it = tid + k * 256;
        const int qi = it >> 7, i = it & 127;
        const int lvl = (i >> 2) & 3;
        const int q = min(q0 + qi, S_TOTAL - 1);

        float refx, refy;
        if (q < 5776)      { int u = q;        int r = u / 76, c = u % 76; refx = (c + 0.5f) / 76.f; refy = (r + 0.5f) / 76.f; }
        else if (q < 7220) { int u = q - 5776; int r = u / 38, c = u % 38; refx = (c + 0.5f) / 38.f; refy = (r + 0.5f) / 38.f; }
        else if (q < 7581) { int u = q - 7220; int r = u / 19, c = u % 19; refx = (c + 0.5f) / 19.f; refy = (r + 0.5f) / 19.f; }
        else               { int u = q - 7581; int r = u / 10, c = u % 10; refx = (c + 0.5f) / 10.f; refy = (r + 0.5f) / 10.f; }

        const int LVL_HW[4] = {76, 38, 19, 10};
        const int LVL_ST[4] = {0, 5776, 7220, 7581};
        const int W = LVL_HW[lvl];
        const float fW = (float)W;

        float ox = soff[qi * 384 + i * 2];
        float oy = soff[qi * 384 + i * 2 + 1];
        float aw = soff[qi * 384 + 256 + i];

        float x = refx * fW + ox - 0.5f;
        float y = refy * fW + oy - 0.5f;
        float x0f = floorf(x), y0f = floorf(y);
        int x0 = (int)x0f, y0 = (int)y0f;
        float dx = x - x0f, dy = y - y0f;

        bool vx0 = (x0 >= 0) & (x0 < W);
        bool vx1 = (x0 >= -1) & (x0 < W - 1);
        bool vy0 = (y0 >= 0) & (y0 < W);
        bool vy1 = (y0 >= -1) & (y0 < W - 1);
        int xc0 = min(max(x0, 0), W - 1), xc1 = min(max(x0 + 1, 0), W - 1);
        int yc0 = min(max(y0, 0), W - 1), yc1 = min(max(y0 + 1, 0), W - 1);
        int base = LVL_ST[lvl];
        rid[k].x = (unsigned short)(base + yc0 * W + xc0);
        rid[k].y = (unsigned short)(base + yc0 * W + xc1);
        rid[k].z = (unsigned short)(base + yc1 * W + xc0);
        rid[k].w = (unsigned short)(base + yc1 * W + xc1);
        rw[k].x = (vy0 && vx0) ? (1.f - dy) * (1.f - dx) * aw : 0.f;
        rw[k].y = (vy0 && vx1) ? (1.f - dy) * dx * aw : 0.f;
        rw[k].z = (vy1 && vx0) ? dy * (1.f - dx) * aw : 0.f;
        rw[k].w = (vy1 && vx1) ? dy * dx * aw : 0.f;
    }
    __syncthreads();   // all soff reads done; safe to overwrite
    #pragma unroll
    for (int k = 0; k < 4; ++k) {
        sIdx[tid + k * 256] = rid[k];
        sWgt[tid + k * 256] = rw[k];
    }
    __syncthreads();

    const int lane = tid & 63;
    const int qi = (tid >> 6) * 2 + (lane >> 5);
    const int q = q0 + qi;
    if (q >= S_TOTAL) return;
    const int l32 = lane & 31;
    const int h = l32 >> 2, dg = l32 & 3;
    const short* vcol = value + h * 32 + dg * 8;
    const int itb = qi * 128 + (h << 4);

    float a[8] = {};
    #pragma unroll
    for (int pt = 0; pt < 16; ++pt) {
        const ushort4 id = sIdx[itb + pt];
        const float4 w = sWgt[itb + pt];
        bf16x8 v0 = *(const bf16x8*)(vcol + ((size_t)id.x << 8));
        bf16x8 v1 = *(const bf16x8*)(vcol + ((size_t)id.y << 8));
        bf16x8 v2 = *(const bf16x8*)(vcol + ((size_t)id.z << 8));
        bf16x8 v3 = *(const bf16x8*)(vcol + ((size_t)id.w << 8));
        #pragma unroll
        for (int e = 0; e < 8; ++e)
            a[e] += w.x * b2f((unsigned short)v0[e]) + w.y * b2f((unsigned short)v1[e])
                  + w.z * b2f((unsigned short)v2[e]) + w.w * b2f((unsigned short)v3[e]);
    }
    bf16x8 o;
    #pragma unroll
    for (int e = 0; e < 8; ++e) o[e] = f2b(a[e]);
    *(bf16x8*)(msdab + (size_t)q * 256 + h * 32 + dg * 8) = o;
}

// ---------------------------------------------------------------------------
// GEMM (N=256 fixed) + residual + LayerNorm fused epilogue.
// BM=32 rows/block (241 blocks), 4 waves each own a 64-col slice.
// Writes: out fp32, xb = bf16(out), and (WRITEQ) qb = bf16(out + pos).
// ---------------------------------------------------------------------------
template<int WRITEQ>
__global__ __launch_bounds__(256) void gemm_ln_kernel(
    const short* __restrict__ A, const short* __restrict__ Wt,
    const float* __restrict__ bias, const float* __restrict__ g,
    const float* __restrict__ bln, const float* __restrict__ pos,
    float* __restrict__ out, short* __restrict__ xb, short* __restrict__ qb,
    int M, int K)
{
    __shared__ __align__(16) short As[32 * KP];
    __shared__ __align__(16) short Bs[256 * KP];
    __shared__ float rsum[32][4], rsq[32][4], smu[32], srs[32];

    const int tid = threadIdx.x;
    const int lane = tid & 63;
    const int wave = tid >> 6;
    const int rowBase = blockIdx.x * 32;

    const int frow = lane & 15;
    const int fko  = (lane >> 4) * 8;

    f32x4 acc[2][4] = {};

    const int ar = tid >> 1;
    const int ak = (tid & 1) * 16;
    const int aRow = rowBase + ar;
    const bool aOk = (tid < 64) && (aRow < M);
    const short* Ap = A + (size_t)aRow * K + ak;
    const short* Bp = Wt + (size_t)tid * K;

    bf16x8 a0 = {}, a1 = {};
    bf16x8 w0, w1, w2, w3;
    if (aOk) { a0 = *(const bf16x8*)Ap; a1 = *(const bf16x8*)(Ap + 8); }
    w0 = *(const bf16x8*)(Bp);      w1 = *(const bf16x8*)(Bp + 8);
    w2 = *(const bf16x8*)(Bp + 16); w3 = *(const bf16x8*)(Bp + 24);

    for (int k0 = 0; k0 < K; k0 += BK) {
        if (tid < 64) {
            *(bf16x8*)&As[ar * KP + ak]     = a0;
            *(bf16x8*)&As[ar * KP + ak + 8] = a1;
        }
        *(bf16x8*)&Bs[tid * KP + 0]  = w0;
        *(bf16x8*)&Bs[tid * KP + 8]  = w1;
        *(bf16x8*)&Bs[tid * KP + 16] = w2;
        *(bf16x8*)&Bs[tid * KP + 24] = w3;
        __syncthreads();

        const int kn = k0 + BK;
        if (kn < K) {
            if (aOk) { a0 = *(const bf16x8*)(Ap + kn); a1 = *(const bf16x8*)(Ap + kn + 8); }
            w0 = *(const bf16x8*)(Bp + kn);      w1 = *(const bf16x8*)(Bp + kn + 8);
            w2 = *(const bf16x8*)(Bp + kn + 16); w3 = *(const bf16x8*)(Bp + kn + 24);
        }

        bf16x8 af0 = *(const bf16x8*)&As[frow * KP + fko];
        bf16x8 af1 = *(const bf16x8*)&As[(16 + frow) * KP + fko];
        #pragma unroll
        for (int j = 0; j < 4; ++j) {
            bf16x8 bfj = *(const bf16x8*)&Bs[(wave * 64 + j * 16 + frow) * KP + fko];
            acc[0][j] = __builtin_amdgcn_mfma_f32_16x16x32_bf16(af0, bfj, acc[0][j], 0, 0, 0);
            acc[1][j] = __builtin_amdgcn_mfma_f32_16x16x32_bf16(af1, bfj, acc[1][j], 0, 0, 0);
        }
        __syncthreads();
    }

    const int erow = (lane >> 4) * 4;
    const int ecol = lane & 15;
    float x[2][4][4];
    #pragma unroll
    for (int mi = 0; mi < 2; ++mi)
        #pragma unroll
        for (int j = 0; j < 4; ++j)
            #pragma unroll
            for (int r = 0; r < 4; ++r) {
                int row = rowBase + mi * 16 + erow + r;
                int col = wave * 64 + j * 16 + ecol;
                float res = (row < M) ? out[(size_t)row * 256 + col] : 0.f;
                x[mi][j][r] = acc[mi][j][r] + bias[col] + res;
            }

    #pragma unroll
    for (int mi = 0; mi < 2; ++mi)
        #pragma unroll
        for (int r = 0; r < 4; ++r) {
            float s1 = x[mi][0][r] + x[mi][1][r] + x[mi][2][r] + x[mi][3][r];
            float s2 = x[mi][0][r]*x[mi][0][r] + x[mi][1][r]*x[mi][1][r]
                     + x[mi][2][r]*x[mi][2][r] + x[mi][3][r]*x[mi][3][r];
            #pragma unroll
            for (int o = 1; o < 16; o <<= 1) {
                s1 += __shfl_xor(s1, o);
                s2 += __shfl_xor(s2, o);
            }
            if ((lane & 15) == 0) {
                rsum[mi * 16 + erow + r][wave] = s1;
                rsq [mi * 16 + erow + r][wave] = s2;
            }
        }
    __syncthreads();
    if (tid < 32) {
        float S1 = rsum[tid][0] + rsum[tid][1] + rsum[tid][2] + rsum[tid][3];
        float S2 = rsq[tid][0] + rsq[tid][1] + rsq[tid][2] + rsq[tid][3];
        float mu = S1 * (1.f / 256.f);
        smu[tid] = mu;
        srs[tid] = rsqrtf(S2 * (1.f / 256.f) - mu * mu + 1e-5f);
    }
    __syncthreads();

    #pragma unroll
    for (int mi = 0; mi < 2; ++mi)
        #pragma unroll
        for (int r = 0; r < 4; ++r) {
            int lrow = mi * 16 + erow + r;
            int row = rowBase + lrow;
            if (row >= M) continue;
            float mu = smu[lrow], rs = srs[lrow];
            #pragma unroll
            for (int j = 0; j < 4; ++j) {
                int col = wave * 64 + j * 16 + ecol;
                float y = (x[mi][j][r] - mu) * rs * g[col] + bln[col];
                out[(size_t)row * 256 + col] = y;
                xb[(size_t)row * 256 + col] = f2b(y);
                if (WRITEQ)
                    qb[(size_t)row * 256 + col] = f2b(y + pos[(size_t)row * 256 + col]);
            }
        }
}

// ---------------------------------------------------------------------------
extern "C" void kernel_launch(void* const* d_in, const int* in_sizes, int n_in,
                              void* d_out, int out_size, void* d_ws, size_t ws_size,
                              hipStream_t stream) {
    const float* src    = (const float*)d_in[0];
    const float* pos    = (const float*)d_in[1];
    const float* W_off  = (const float*)d_in[6];
    const float* b_off  = (const float*)d_in[7];
    const float* W_attn = (const float*)d_in[8];
    const float* b_attn = (const float*)d_in[9];
    const float* W_val  = (const float*)d_in[10];
    const float* b_val  = (const float*)d_in[11];
    const float* W_out  = (const float*)d_in[12];
    const float* b_out  = (const float*)d_in[13];
    const float* ln1_g  = (const float*)d_in[14];
    const float* ln1_b  = (const float*)d_in[15];
    const float* W_ff1  = (const float*)d_in[16];
    const float* b_ff1  = (const float*)d_in[17];
    const float* W_ff2  = (const float*)d_in[18];
    const float* b_ff2  = (const float*)d_in[19];
    const float* ln2_g  = (const float*)d_in[20];
    const float* ln2_b  = (const float*)d_in[21];

    const size_t S = S_TOTAL;
    float* out = (float*)d_out;

    // --- workspace layout ---
    short* wt = (short*)d_ws;
    short* Wt_val = wt;             // 3 x [256][256]
    short* Wt_oa  = wt + 196608;    // 3 x [384][256] (off rows 0-255, attn 256-383)
    short* Wt_out = wt + 491520;    // 3 x [256][256]
    short* Wt_ff1 = wt + 688128;    // 3 x [1024][256]
    short* Wt_ff2 = wt + 1474560;   // 3 x [256][1024]
    float* fbase  = (float*)d_ws + 1131648;
    short* xb       = (short*)fbase;               // [S][256] bf16
    short* qb       = (short*)(fbase + 128 * S);   // [S][256] bf16
    short* value_bf = (short*)(fbase + 256 * S);   // [S][256] bf16
    float* offb     = fbase + 384 * S;             // [S][384] fp32
    short* msdab    = (short*)(fbase + 768 * S);   // [S][256] bf16
    short* hid      = (short*)(fbase + 256 * S);   // [S][1024] bf16 (FFN; overlaps value+offb)

    prologue_kernel<<<4129, 256, 0, stream>>>(
        W_val, W_off, W_attn, W_out, W_ff1, W_ff2,
        Wt_val, Wt_oa, Wt_oa + 65536, Wt_out, Wt_ff1, Wt_ff2,
        (const float4*)src, (const float4*)pos,
        (float4*)out, (ushort4*)xb, (ushort4*)qb);

    const int MB = (S_TOTAL + BM - 1) / BM;   // 61
    const int LB = (S_TOTAL + 31) / 32;       // 241

    for (int l = 0; l < 3; ++l) {
        // value (bf16) + off/attn (fp32) in one dispatch
        gemm_va_kernel<<<dim3(MB, 10), 256, 0, stream>>>(
            xb, qb, Wt_val + (size_t)l * 65536, Wt_oa + (size_t)l * 98304,
            b_val + (size_t)l * 256, b_off + (size_t)l * 256, b_attn + (size_t)l * 128,
            value_bf, offb, S_TOTAL);
        // sampling -> bf16 msdab
        msda_kernel<<<968, 256, 0, stream>>>(value_bf, offb, msdab);
        // out = LN1(out + msdab @ Wout + bout); xb = bf16(out)
        gemm_ln_kernel<0><<<LB, 256, 0, stream>>>(
            msdab, Wt_out + (size_t)l * 65536, b_out + (size_t)l * 256,
            ln1_g + (size_t)l * 256, ln1_b + (size_t)l * 256, pos,
            out, xb, qb, S_TOTAL, 256);
        // hid = bf16(relu(xb @ Wff1 + b))
        gemm_ff1_kernel<<<dim3(MB, 16), 256, 0, stream>>>(
            xb, Wt_ff1 + (size_t)l * 262144, b_ff1 + (size_t)l * 1024, hid,
            S_TOTAL, 1024, 256);
        // out = LN2(out + hid @ Wff2 + b); xb, qb for next layer
        gemm_ln_kernel<1><<<LB, 256, 0, stream>>>(
            hid, Wt_ff2 + (size_t)l * 262144, b_ff2 + (size_t)l * 256,
            ln2_g + (size_t)l * 256, ln2_b + (size_t)l * 256, pos,
            out, xb, qb, S_TOTAL, 1024);
    }
}

// Round 8
// 426.684 us; speedup vs baseline: 1.0579x; 1.0323x over previous
//
#include <hip/hip_runtime.h>
#include <hip/hip_bf16.h>
#include <math.h>

#define S_TOTAL 7681

typedef __attribute__((ext_vector_type(8))) short bf16x8;
typedef __attribute__((ext_vector_type(4))) float f32x4;

// fp32 -> bf16 round-to-nearest-even
__device__ __forceinline__ short f2b(float x) {
    union { float f; unsigned u; } v; v.f = x;
    unsigned r = v.u + 0x7FFFu + ((v.u >> 16) & 1u);
    return (short)(r >> 16);
}
__device__ __forceinline__ float b2f(unsigned short u) {
    union { unsigned u; float f; } t; t.u = ((unsigned)u) << 16; return t.f;
}

#define BM 128
#define BN 64
#define BK 64
#define KP 72   // 64 + 8 pad shorts; 144 B row stride (16B aligned)

// ---------------------------------------------------------------------------
// Weight transpose + convert. W[K][N] fp32 -> Wt[N][K] bf16. grid (736,1,3)
// ---------------------------------------------------------------------------
__global__ __launch_bounds__(256) void transpose_cvt_kernel(
    const float* __restrict__ s0, const float* __restrict__ s1,
    const float* __restrict__ s2, const float* __restrict__ s3,
    const float* __restrict__ s4, const float* __restrict__ s5,
    short* __restrict__ d0, short* __restrict__ d1, short* __restrict__ d2,
    short* __restrict__ d3, short* __restrict__ d4, short* __restrict__ d5)
{
    const int z = blockIdx.z;
    int t = blockIdx.x;
    const float* src_w; short* dst; int K, N, lt;
    if (t < 64)       { src_w = s0 + (size_t)z * 65536;  dst = d0 + (size_t)z * 65536;  K = 256;  N = 256;  lt = t; }
    else if (t < 128) { src_w = s1 + (size_t)z * 65536;  dst = d1 + (size_t)z * 98304;  K = 256;  N = 256;  lt = t - 64; }
    else if (t < 160) { src_w = s2 + (size_t)z * 32768;  dst = d2 + (size_t)z * 98304;  K = 256;  N = 128;  lt = t - 128; }
    else if (t < 224) { src_w = s3 + (size_t)z * 65536;  dst = d3 + (size_t)z * 65536;  K = 256;  N = 256;  lt = t - 160; }
    else if (t < 480) { src_w = s4 + (size_t)z * 262144; dst = d4 + (size_t)z * 262144; K = 256;  N = 1024; lt = t - 224; }
    else              { src_w = s5 + (size_t)z * 262144; dst = d5 + (size_t)z * 262144; K = 1024; N = 256;  lt = t - 480; }
    const int ntx = N >> 5;
    const int tk = (lt / ntx) << 5, tn = (lt % ntx) << 5;
    __shared__ float tile[32][33];
    const int cx = threadIdx.x & 31, cy = threadIdx.x >> 5;
    #pragma unroll
    for (int i = 0; i < 32; i += 8)
        tile[cy + i][cx] = src_w[(size_t)(tk + cy + i) * N + tn + cx];
    __syncthreads();
    #pragma unroll
    for (int i = 0; i < 32; i += 8)
        dst[(size_t)(tn + cy + i) * K + tk + cx] = f2b(tile[cx][cy + i]);
}

// out = src; xb = bf16(src); qb = bf16(src + pos)
__global__ __launch_bounds__(256) void cvt_copy_kernel(
    const float4* __restrict__ src, const float4* __restrict__ pos,
    float4* __restrict__ o, ushort4* __restrict__ xb, ushort4* __restrict__ qb,
    int n4)
{
    int i = blockIdx.x * blockDim.x + threadIdx.x;
    if (i < n4) {
        float4 v = src[i], p = pos[i];
        o[i] = v;
        ushort4 h, hq;
        h.x = (unsigned short)f2b(v.x); h.y = (unsigned short)f2b(v.y);
        h.z = (unsigned short)f2b(v.z); h.w = (unsigned short)f2b(v.w);
        hq.x = (unsigned short)f2b(v.x + p.x); hq.y = (unsigned short)f2b(v.y + p.y);
        hq.z = (unsigned short)f2b(v.z + p.z); hq.w = (unsigned short)f2b(v.w + p.w);
        xb[i] = h;
        qb[i] = hq;
    }
}

// ---------------------------------------------------------------------------
// Merged value + off/attn GEMM (K=256, BK=64). grid (61, 10):
//  y in [0,4): value_bf[S][256] (bf16) = xb @ Wt_val^T + b_val
//  y in [4,10): offb[S][384] (fp32) = qb @ Wt_oa^T + {b_off|b_attn}
// ---------------------------------------------------------------------------
__global__ __launch_bounds__(256) void gemm_va_kernel(
    const short* __restrict__ xb, const short* __restrict__ qb,
    const short* __restrict__ Wt_val, const short* __restrict__ Wt_oa,
    const float* __restrict__ b_val, const float* __restrict__ b_off,
    const float* __restrict__ b_attn,
    short* __restrict__ value_bf, float* __restrict__ offbuf, int M)
{
    const int grp = (blockIdx.y >= 4);
    const short* A  = grp ? qb : xb;
    const short* Wt = grp ? Wt_oa : Wt_val;
    const int colBase = (grp ? (blockIdx.y - 4) : blockIdx.y) * BN;
    const int K = 256;

    __shared__ __align__(16) short As[BM * KP];   // 18432 B
    __shared__ __align__(16) short Bs[BN * KP];   //  9216 B
    const int tid = threadIdx.x;
    const int lane = tid & 63;
    const int wave = tid >> 6;
    const int rowBase = blockIdx.x * BM;

    const int ar = tid >> 1;          // 0..127
    const int ak = (tid & 1) * 32;    // 32 shorts per thread
    const int br = tid >> 2;          // 0..63
    const int bk = (tid & 3) * 16;    // 16 shorts per thread

    const int frow = lane & 15;
    const int fko  = (lane >> 4) * 8;
    const int wm = wave * 32;

    f32x4 acc[2][4] = {};

    const int aRow = rowBase + ar;
    const bool aOk = aRow < M;
    const short* Ap = A + (size_t)aRow * K + ak;
    const short* Bp = Wt + (size_t)(colBase + br) * K + bk;

    bf16x8 a0 = {}, a1 = {}, a2 = {}, a3 = {}, b0 = {}, b1 = {};
    if (aOk) {
        a0 = *(const bf16x8*)Ap;        a1 = *(const bf16x8*)(Ap + 8);
        a2 = *(const bf16x8*)(Ap + 16); a3 = *(const bf16x8*)(Ap + 24);
    }
    b0 = *(const bf16x8*)Bp; b1 = *(const bf16x8*)(Bp + 8);

    for (int k0 = 0; k0 < K; k0 += BK) {
        *(bf16x8*)&As[ar * KP + ak]      = a0;
        *(bf16x8*)&As[ar * KP + ak + 8]  = a1;
        *(bf16x8*)&As[ar * KP + ak + 16] = a2;
        *(bf16x8*)&As[ar * KP + ak + 24] = a3;
        *(bf16x8*)&Bs[br * KP + bk]      = b0;
        *(bf16x8*)&Bs[br * KP + bk + 8]  = b1;
        __syncthreads();

        const int kn = k0 + BK;
        if (kn < K) {
            if (aOk) {
                a0 = *(const bf16x8*)(Ap + kn);      a1 = *(const bf16x8*)(Ap + kn + 8);
                a2 = *(const bf16x8*)(Ap + kn + 16); a3 = *(const bf16x8*)(Ap + kn + 24);
            }
            b0 = *(const bf16x8*)(Bp + kn); b1 = *(const bf16x8*)(Bp + kn + 8);
        }

        #pragma unroll
        for (int kk = 0; kk < 2; ++kk) {
            bf16x8 af0 = *(const bf16x8*)&As[(wm + frow) * KP + kk * 32 + fko];
            bf16x8 af1 = *(const bf16x8*)&As[(wm + 16 + frow) * KP + kk * 32 + fko];
            #pragma unroll
            for (int j = 0; j < 4; ++j) {
                bf16x8 bfj = *(const bf16x8*)&Bs[(j * 16 + frow) * KP + kk * 32 + fko];
                acc[0][j] = __builtin_amdgcn_mfma_f32_16x16x32_bf16(af0, bfj, acc[0][j], 0, 0, 0);
                acc[1][j] = __builtin_amdgcn_mfma_f32_16x16x32_bf16(af1, bfj, acc[1][j], 0, 0, 0);
            }
        }
        __syncthreads();
    }

    const int erow = (lane >> 4) * 4;
    const int ecol = lane & 15;
    #pragma unroll
    for (int mi = 0; mi < 2; ++mi) {
        #pragma unroll
        for (int j = 0; j < 4; ++j) {
            int col = colBase + j * 16 + ecol;
            float bias = grp ? (col < 256 ? b_off[col] : b_attn[col - 256]) : b_val[col];
            #pragma unroll
            for (int r = 0; r < 4; ++r) {
                int row = rowBase + wm + mi * 16 + erow + r;
                if (row < M) {
                    float v = acc[mi][j][r] + bias;
                    if (grp) offbuf[(size_t)row * 384 + col] = v;
                    else     value_bf[(size_t)row * 256 + col] = f2b(v);
                }
            }
        }
    }
}

// ---------------------------------------------------------------------------
// bf16 MFMA GEMM + bias + relu -> bf16 (ff1). BM=128, BN=64, BK=64.
// ---------------------------------------------------------------------------
__global__ __launch_bounds__(256) void gemm_ff1_kernel(
    const short* __restrict__ A, const short* __restrict__ Wt,
    const float* __restrict__ bias, short* __restrict__ Cv,
    int M, int N, int K)
{
    __shared__ __align__(16) short As[BM * KP];
    __shared__ __align__(16) short Bs[BN * KP];
    const int tid = threadIdx.x;
    const int lane = tid & 63;
    const int wave = tid >> 6;
    const int rowBase = blockIdx.x * BM;
    const int colBase = blockIdx.y * BN;

    const int ar = tid >> 1;
    const int ak = (tid & 1) * 32;
    const int br = tid >> 2;
    const int bk = (tid & 3) * 16;

    const int frow = lane & 15;
    const int fko  = (lane >> 4) * 8;
    const int wm = wave * 32;

    f32x4 acc[2][4] = {};

    const int aRow = rowBase + ar;
    const bool aOk = aRow < M;
    const short* Ap = A + (size_t)aRow * K + ak;
    const short* Bp = Wt + (size_t)(colBase + br) * K + bk;

    bf16x8 a0 = {}, a1 = {}, a2 = {}, a3 = {}, b0 = {}, b1 = {};
    if (aOk) {
        a0 = *(const bf16x8*)Ap;        a1 = *(const bf16x8*)(Ap + 8);
        a2 = *(const bf16x8*)(Ap + 16); a3 = *(const bf16x8*)(Ap + 24);
    }
    b0 = *(const bf16x8*)Bp; b1 = *(const bf16x8*)(Bp + 8);

    for (int k0 = 0; k0 < K; k0 += BK) {
        *(bf16x8*)&As[ar * KP + ak]      = a0;
        *(bf16x8*)&As[ar * KP + ak + 8]  = a1;
        *(bf16x8*)&As[ar * KP + ak + 16] = a2;
        *(bf16x8*)&As[ar * KP + ak + 24] = a3;
        *(bf16x8*)&Bs[br * KP + bk]      = b0;
        *(bf16x8*)&Bs[br * KP + bk + 8]  = b1;
        __syncthreads();

        const int kn = k0 + BK;
        if (kn < K) {
            if (aOk) {
                a0 = *(const bf16x8*)(Ap + kn);      a1 = *(const bf16x8*)(Ap + kn + 8);
                a2 = *(const bf16x8*)(Ap + kn + 16); a3 = *(const bf16x8*)(Ap + kn + 24);
            }
            b0 = *(const bf16x8*)(Bp + kn); b1 = *(const bf16x8*)(Bp + kn + 8);
        }

        #pragma unroll
        for (int kk = 0; kk < 2; ++kk) {
            bf16x8 af0 = *(const bf16x8*)&As[(wm + frow) * KP + kk * 32 + fko];
            bf16x8 af1 = *(const bf16x8*)&As[(wm + 16 + frow) * KP + kk * 32 + fko];
            #pragma unroll
            for (int j = 0; j < 4; ++j) {
                bf16x8 bfj = *(const bf16x8*)&Bs[(j * 16 + frow) * KP + kk * 32 + fko];
                acc[0][j] = __builtin_amdgcn_mfma_f32_16x16x32_bf16(af0, bfj, acc[0][j], 0, 0, 0);
                acc[1][j] = __builtin_amdgcn_mfma_f32_16x16x32_bf16(af1, bfj, acc[1][j], 0, 0, 0);
            }
        }
        __syncthreads();
    }

    const int erow = (lane >> 4) * 4;
    const int ecol = lane & 15;
    #pragma unroll
    for (int mi = 0; mi < 2; ++mi) {
        #pragma unroll
        for (int j = 0; j < 4; ++j) {
            #pragma unroll
            for (int r = 0; r < 4; ++r) {
                int row = rowBase + wm + mi * 16 + erow + r;
                if (row < M) {
                    int col = colBase + j * 16 + ecol;
                    float v = fmaxf(acc[mi][j][r] + bias[col], 0.f);
                    Cv[(size_t)row * N + col] = f2b(v);
                }
            }
        }
    }
}

// ---------------------------------------------------------------------------
// MSDA sampling v5 (unchanged from R7): 8 queries/block, ushort8 gathers,
// 24.6 KB LDS via phase-aliasing. grid = 968.
// ---------------------------------------------------------------------------
__global__ __launch_bounds__(256) void msda_kernel(
    const short* __restrict__ value, const float* __restrict__ offb,
    short* __restrict__ msdab)
{
    __shared__ __align__(16) char scratch[24576];
    float*   soff = (float*)scratch;
    ushort4* sIdx = (ushort4*)scratch;
    float4*  sWgt = (float4*)(scratch + 8192);

    const int bid = blockIdx.x;
    const int sb = (bid & 7) * 121 + (bid >> 3);
    const int q0 = sb * 8;
    if (q0 >= S_TOTAL) return;
    const int tid = threadIdx.x;

    {
        const float4* src4 = (const float4*)offb;
        float4* soff4 = (float4*)soff;
        #pragma unroll
        for (int i = tid; i < 768; i += 256) {
            int qi = i / 96, j = i - qi * 96;
            int q = min(q0 + qi, S_TOTAL - 1);
            soff4[qi * 96 + j] = src4[(size_t)q * 96 + j];
        }
    }
    __syncthreads();

    if (tid < 64) {
        const int qi = tid >> 3, m = tid & 7;
        float* lg = &soff[qi * 384 + 256 + m * 16];
        float mx = -1e30f;
        #pragma unroll
        for (int k = 0; k < 16; ++k) mx = fmaxf(mx, lg[k]);
        float e[16], sum = 0.f;
        #pragma unroll
        for (int k = 0; k < 16; ++k) { e[k] = expf(lg[k] - mx); sum += e[k]; }
        float inv = 1.f / sum;
        #pragma unroll
        for (int k = 0; k < 16; ++k) lg[k] = e[k] * inv;
    }
    __syncthreads();

    ushort4 rid[4];
    float4  rw[4];
    #pragma unroll
    for (int k = 0; k < 4; ++k) {
        const int it = tid + k * 256;
        const int qi = it >> 7, i = it & 127;
        const int lvl = (i >> 2) & 3;
        const int q = min(q0 + qi, S_TOTAL - 1);

        float refx, refy;
        if (q < 5776)      { int u = q;        int r = u / 76, c = u % 76; refx = (c + 0.5f) / 76.f; refy = (r + 0.5f) / 76.f; }
        else if (q < 7220) { int u = q - 5776; int r = u / 38, c = u % 38; refx = (c + 0.5f) / 38.f; refy = (r + 0.5f) / 38.f; }
        else if (q < 7581) { int u = q - 7220; int r = u / 19, c = u % 19; refx = (c + 0.5f) / 19.f; refy = (r + 0.5f) / 19.f; }
        else               { int u = q - 7581; int r = u / 10, c = u % 10; refx = (c + 0.5f) / 10.f; refy = (r + 0.5f) / 10.f; }

        const int LVL_HW[4] = {76, 38, 19, 10};
        const int LVL_ST[4] = {0, 5776, 7220, 7581};
        const int W = LVL_HW[lvl];
        const float fW = (float)W;

        float ox = soff[qi * 384 + i * 2];
        float oy = soff[qi * 384 + i * 2 + 1];
        float aw = soff[qi * 384 + 256 + i];

        float x = refx * fW + ox - 0.5f;
        float y = refy * fW + oy - 0.5f;
        float x0f = floorf(x), y0f = floorf(y);
        int x0 = (int)x0f, y0 = (int)y0f;
        float dx = x - x0f, dy = y - y0f;

        bool vx0 = (x0 >= 0) & (x0 < W);
        bool vx1 = (x0 >= -1) & (x0 < W - 1);
        bool vy0 = (y0 >= 0) & (y0 < W);
        bool vy1 = (y0 >= -1) & (y0 < W - 1);
        int xc0 = min(max(x0, 0), W - 1), xc1 = min(max(x0 + 1, 0), W - 1);
        int yc0 = min(max(y0, 0), W - 1), yc1 = min(max(y0 + 1, 0), W - 1);
        int base = LVL_ST[lvl];
        rid[k].x = (unsigned short)(base + yc0 * W + xc0);
        rid[k].y = (unsigned short)(base + yc0 * W + xc1);
        rid[k].z = (unsigned short)(base + yc1 * W + xc0);
        rid[k].w = (unsigned short)(base + yc1 * W + xc1);
        rw[k].x = (vy0 && vx0) ? (1.f - dy) * (1.f - dx) * aw : 0.f;
        rw[k].y = (vy0 && vx1) ? (1.f - dy) * dx * aw : 0.f;
        rw[k].z = (vy1 && vx0) ? dy * (1.f - dx) * aw : 0.f;
        rw[k].w = (vy1 && vx1) ? dy * dx * aw : 0.f;
    }
    __syncthreads();
    #pragma unroll
    for (int k = 0; k < 4; ++k) {
        sIdx[tid + k * 256] = rid[k];
        sWgt[tid + k * 256] = rw[k];
    }
    __syncthreads();

    const int lane = tid & 63;
    const int qi = (tid >> 6) * 2 + (lane >> 5);
    const int q = q0 + qi;
    if (q >= S_TOTAL) return;
    const int l32 = lane & 31;
    const int h = l32 >> 2, dg = l32 & 3;
    const short* vcol = value + h * 32 + dg * 8;
    const int itb = qi * 128 + (h << 4);

    float a[8] = {};
    #pragma unroll
    for (int pt = 0; pt < 16; ++pt) {
        const ushort4 id = sIdx[itb + pt];
        const float4 w = sWgt[itb + pt];
        bf16x8 v0 = *(const bf16x8*)(vcol + ((size_t)id.x << 8));
        bf16x8 v1 = *(const bf16x8*)(vcol + ((size_t)id.y << 8));
        bf16x8 v2 = *(const bf16x8*)(vcol + ((size_t)id.z << 8));
        bf16x8 v3 = *(const bf16x8*)(vcol + ((size_t)id.w << 8));
        #pragma unroll
        for (int e = 0; e < 8; ++e)
            a[e] += w.x * b2f((unsigned short)v0[e]) + w.y * b2f((unsigned short)v1[e])
                  + w.z * b2f((unsigned short)v2[e]) + w.w * b2f((unsigned short)v3[e]);
    }
    bf16x8 o;
    #pragma unroll
    for (int e = 0; e < 8; ++e) o[e] = f2b(a[e]);
    *(bf16x8*)(msdab + (size_t)q * 256 + h * 32 + dg * 8) = o;
}

// ---------------------------------------------------------------------------
// GEMM (N=256) + residual + LayerNorm. BM=32 (241 blocks), BK=64.
// Writes out fp32, xb bf16, (WRITEQ) qb = bf16(out + pos).
// ---------------------------------------------------------------------------
template<int WRITEQ>
__global__ __launch_bounds__(256) void gemm_ln_kernel(
    const short* __restrict__ A, const short* __restrict__ Wt,
    const float* __restrict__ bias, const float* __restrict__ g,
    const float* __restrict__ bln, const float* __restrict__ pos,
    float* __restrict__ out, short* __restrict__ xb, short* __restrict__ qb,
    int M, int K)
{
    __shared__ __align__(16) short As[32 * KP];    //  4608 B
    __shared__ __align__(16) short Bs[256 * KP];   // 36864 B
    __shared__ float rsum[32][4], rsq[32][4], smu[32], srs[32];

    const int tid = threadIdx.x;
    const int lane = tid & 63;
    const int wave = tid >> 6;
    const int rowBase = blockIdx.x * 32;

    const int frow = lane & 15;
    const int fko  = (lane >> 4) * 8;

    f32x4 acc[2][4] = {};

    const int ar = tid >> 2;            // valid for tid<128: rows 0..31
    const int ak = (tid & 3) * 16;      // 16 shorts per thread
    const int aRow = rowBase + ar;
    const bool aOk = (tid < 128) && (aRow < M);
    const short* Ap = A + (size_t)aRow * K + ak;
    const short* Bp = Wt + (size_t)tid * K;

    bf16x8 a0 = {}, a1 = {};
    bf16x8 w[8];
    if (aOk) { a0 = *(const bf16x8*)Ap; a1 = *(const bf16x8*)(Ap + 8); }
    #pragma unroll
    for (int i = 0; i < 8; ++i) w[i] = *(const bf16x8*)(Bp + i * 8);

    for (int k0 = 0; k0 < K; k0 += BK) {
        if (tid < 128) {
            *(bf16x8*)&As[ar * KP + ak]     = a0;
            *(bf16x8*)&As[ar * KP + ak + 8] = a1;
        }
        #pragma unroll
        for (int i = 0; i < 8; ++i)
            *(bf16x8*)&Bs[tid * KP + i * 8] = w[i];
        __syncthreads();

        const int kn = k0 + BK;
        if (kn < K) {
            if (aOk) { a0 = *(const bf16x8*)(Ap + kn); a1 = *(const bf16x8*)(Ap + kn + 8); }
            #pragma unroll
            for (int i = 0; i < 8; ++i) w[i] = *(const bf16x8*)(Bp + kn + i * 8);
        }

        #pragma unroll
        for (int kk = 0; kk < 2; ++kk) {
            bf16x8 af = *(const bf16x8*)&As[frow * KP + kk * 32 + fko];
            bf16x8 af1 = *(const bf16x8*)&As[(16 + frow) * KP + kk * 32 + fko];
            #pragma unroll
            for (int j = 0; j < 4; ++j) {
                bf16x8 bfj = *(const bf16x8*)&Bs[(wave * 64 + j * 16 + frow) * KP + kk * 32 + fko];
                acc[0][j] = __builtin_amdgcn_mfma_f32_16x16x32_bf16(af,  bfj, acc[0][j], 0, 0, 0);
                acc[1][j] = __builtin_amdgcn_mfma_f32_16x16x32_bf16(af1, bfj, acc[1][j], 0, 0, 0);
            }
        }
        __syncthreads();
    }

    const int erow = (lane >> 4) * 4;
    const int ecol = lane & 15;
    float x[2][4][4];
    #pragma unroll
    for (int mi = 0; mi < 2; ++mi)
        #pragma unroll
        for (int j = 0; j < 4; ++j)
            #pragma unroll
            for (int r = 0; r < 4; ++r) {
                int row = rowBase + mi * 16 + erow + r;
                int col = wave * 64 + j * 16 + ecol;
                float res = (row < M) ? out[(size_t)row * 256 + col] : 0.f;
                x[mi][j][r] = acc[mi][j][r] + bias[col] + res;
            }

    #pragma unroll
    for (int mi = 0; mi < 2; ++mi)
        #pragma unroll
        for (int r = 0; r < 4; ++r) {
            float s1 = x[mi][0][r] + x[mi][1][r] + x[mi][2][r] + x[mi][3][r];
            float s2 = x[mi][0][r]*x[mi][0][r] + x[mi][1][r]*x[mi][1][r]
                     + x[mi][2][r]*x[mi][2][r] + x[mi][3][r]*x[mi][3][r];
            #pragma unroll
            for (int o = 1; o < 16; o <<= 1) {
                s1 += __shfl_xor(s1, o);
                s2 += __shfl_xor(s2, o);
            }
            if ((lane & 15) == 0) {
                rsum[mi * 16 + erow + r][wave] = s1;
                rsq [mi * 16 + erow + r][wave] = s2;
            }
        }
    __syncthreads();
    if (tid < 32) {
        float S1 = rsum[tid][0] + rsum[tid][1] + rsum[tid][2] + rsum[tid][3];
        float S2 = rsq[tid][0] + rsq[tid][1] + rsq[tid][2] + rsq[tid][3];
        float mu = S1 * (1.f / 256.f);
        smu[tid] = mu;
        srs[tid] = rsqrtf(S2 * (1.f / 256.f) - mu * mu + 1e-5f);
    }
    __syncthreads();

    #pragma unroll
    for (int mi = 0; mi < 2; ++mi)
        #pragma unroll
        for (int r = 0; r < 4; ++r) {
            int lrow = mi * 16 + erow + r;
            int row = rowBase + lrow;
            if (row >= M) continue;
            float mu = smu[lrow], rs = srs[lrow];
            #pragma unroll
            for (int j = 0; j < 4; ++j) {
                int col = wave * 64 + j * 16 + ecol;
                float y = (x[mi][j][r] - mu) * rs * g[col] + bln[col];
                out[(size_t)row * 256 + col] = y;
                xb[(size_t)row * 256 + col] = f2b(y);
                if (WRITEQ)
                    qb[(size_t)row * 256 + col] = f2b(y + pos[(size_t)row * 256 + col]);
            }
        }
}

// ---------------------------------------------------------------------------
extern "C" void kernel_launch(void* const* d_in, const int* in_sizes, int n_in,
                              void* d_out, int out_size, void* d_ws, size_t ws_size,
                              hipStream_t stream) {
    const float* src    = (const float*)d_in[0];
    const float* pos    = (const float*)d_in[1];
    const float* W_off  = (const float*)d_in[6];
    const float* b_off  = (const float*)d_in[7];
    const float* W_attn = (const float*)d_in[8];
    const float* b_attn = (const float*)d_in[9];
    const float* W_val  = (const float*)d_in[10];
    const float* b_val  = (const float*)d_in[11];
    const float* W_out  = (const float*)d_in[12];
    const float* b_out  = (const float*)d_in[13];
    const float* ln1_g  = (const float*)d_in[14];
    const float* ln1_b  = (const float*)d_in[15];
    const float* W_ff1  = (const float*)d_in[16];
    const float* b_ff1  = (const float*)d_in[17];
    const float* W_ff2  = (const float*)d_in[18];
    const float* b_ff2  = (const float*)d_in[19];
    const float* ln2_g  = (const float*)d_in[20];
    const float* ln2_b  = (const float*)d_in[21];

    const size_t S = S_TOTAL;
    float* out = (float*)d_out;

    // --- workspace layout ---
    short* wt = (short*)d_ws;
    short* Wt_val = wt;             // 3 x [256][256]
    short* Wt_oa  = wt + 196608;    // 3 x [384][256]
    short* Wt_out = wt + 491520;    // 3 x [256][256]
    short* Wt_ff1 = wt + 688128;    // 3 x [1024][256]
    short* Wt_ff2 = wt + 1474560;   // 3 x [256][1024]
    float* fbase  = (float*)d_ws + 1131648;
    short* xb       = (short*)fbase;               // [S][256] bf16
    short* qb       = (short*)(fbase + 128 * S);   // [S][256] bf16
    short* value_bf = (short*)(fbase + 256 * S);   // [S][256] bf16
    float* offb     = fbase + 384 * S;             // [S][384] fp32
    short* msdab    = (short*)(fbase + 768 * S);   // [S][256] bf16
    short* hid      = (short*)(fbase + 256 * S);   // [S][1024] bf16 (FFN; overlaps value+offb)

    transpose_cvt_kernel<<<dim3(736, 1, 3), 256, 0, stream>>>(
        W_val, W_off, W_attn, W_out, W_ff1, W_ff2,
        Wt_val, Wt_oa, Wt_oa + 65536, Wt_out, Wt_ff1, Wt_ff2);

    const int n4 = (int)(S * 256 / 4);
    const int g4 = (n4 + 255) / 256;
    cvt_copy_kernel<<<g4, 256, 0, stream>>>((const float4*)src, (const float4*)pos,
                                            (float4*)out, (ushort4*)xb, (ushort4*)qb, n4);

    const int MB = (S_TOTAL + BM - 1) / BM;   // 61
    const int LB = (S_TOTAL + 31) / 32;       // 241

    for (int l = 0; l < 3; ++l) {
        gemm_va_kernel<<<dim3(MB, 10), 256, 0, stream>>>(
            xb, qb, Wt_val + (size_t)l * 65536, Wt_oa + (size_t)l * 98304,
            b_val + (size_t)l * 256, b_off + (size_t)l * 256, b_attn + (size_t)l * 128,
            value_bf, offb, S_TOTAL);
        msda_kernel<<<968, 256, 0, stream>>>(value_bf, offb, msdab);
        gemm_ln_kernel<0><<<LB, 256, 0, stream>>>(
            msdab, Wt_out + (size_t)l * 65536, b_out + (size_t)l * 256,
            ln1_g + (size_t)l * 256, ln1_b + (size_t)l * 256, pos,
            out, xb, qb, S_TOTAL, 256);
        gemm_ff1_kernel<<<dim3(MB, 16), 256, 0, stream>>>(
            xb, Wt_ff1 + (size_t)l * 262144, b_ff1 + (size_t)l * 1024, hid,
            S_TOTAL, 1024, 256);
        gemm_ln_kernel<1><<<LB, 256, 0, stream>>>(
            hid, Wt_ff2 + (size_t)l * 262144, b_ff2 + (size_t)l * 256,
            ln2_g + (size_t)l * 256, ln2_b + (size_t)l * 256, pos,
            out, xb, qb, S_TOTAL, 1024);
    }
}